// Round 1
// 930.509 us; speedup vs baseline: 1.1252x; 1.1252x over previous
//
#include <hip/hip_runtime.h>
#include <hip/hip_bf16.h>
#include <math.h>

#define Bn   384
#define INn  512
#define OUTn 384

typedef __bf16 bf16x8 __attribute__((ext_vector_type(8)));
typedef __bf16 bf16x4 __attribute__((ext_vector_type(4)));
typedef float  f32x4  __attribute__((ext_vector_type(4)));

// Device-global scratch (no assumption about ws_size).
__device__ __bf16 g_Wbf[OUTn * INn];                 // W cast to bf16, [o][i]
__device__ float  g_sp [OUTn * INn];                 // softplus(sigma_weight)
__device__ float  g_d  [Bn * OUTn];                  // s1+s3 diagonal vector
__device__ float  g_t  [Bn * INn];                   // diag(sigma_b), fp32
__device__ __bf16 g_U  [(size_t)Bn * OUTn * INn];    // U[b][p][i] = sum_j sigma[b,i,j]*W[p,j]

// ---------------------------------------------------------------------------
// prep: Wbf = bf16(W); sp = softplus(sigma_weight)
// ---------------------------------------------------------------------------
__global__ __launch_bounds__(256) void prep_kernel(const float* __restrict__ W,
                                                   const float* __restrict__ sw) {
    int idx = blockIdx.x * 256 + threadIdx.x;
    if (idx < OUTn * INn) {
        g_Wbf[idx] = (__bf16)W[idx];
        float x = sw[idx];
        g_sp[idx] = (x > 20.f) ? x : log1pf(expf(x));
    }
}

// ---------------------------------------------------------------------------
// passA: U[b][p][i] = sum_j sigma[b,i,j] * W[p,j]  (bf16 out)
// grid (8 i-tiles, 384 b), 512 thr. Each block reads a DISJOINT 64-row sigma
// chunk -> sigma fetched from HBM exactly once. Diagonal extracted for free
// during staging (fp32 -> g_t). LDS 64x520x2 = 66,560 B -> 2 blocks/CU.
// MFMA: M=i(64, 4 frags), N=p(48/wave, 3 frags), K=j(512).
// D layout: row(i)=quad*4+r, col(p)=l15 (same convention as verified Stage A).
// ---------------------------------------------------------------------------
__global__ __launch_bounds__(512, 4) void passA_kernel(const float* __restrict__ sigma) {
    __shared__ __bf16 As[64][INn + 8];   // stride 520*2B -> 4-bank row step

    const int it   = blockIdx.x;    // 0..7
    const int b    = blockIdx.y;    // 0..383
    const int tid  = threadIdx.x;
    const int wave = tid >> 6, lane = tid & 63;
    const int quad = lane >> 4, l15 = lane & 15;
    const int i0   = it * 64;

    const float* sigb = sigma + (size_t)b * (INn * INn) + (size_t)i0 * INn;

    // ---- stage sigma chunk (64 rows x 512 f32) -> bf16 LDS; grab diagonal ----
#pragma unroll
    for (int k = 0; k < 8; ++k) {
        const int r = k * 8 + wave;                       // one row per wave
        const float* rp = sigb + (size_t)r * INn + lane * 8;
        float4 a0 = *(const float4*)rp;
        float4 a1 = *(const float4*)(rp + 4);
        bf16x8 t;
        t[0]=(__bf16)a0.x; t[1]=(__bf16)a0.y; t[2]=(__bf16)a0.z; t[3]=(__bf16)a0.w;
        t[4]=(__bf16)a1.x; t[5]=(__bf16)a1.y; t[6]=(__bf16)a1.z; t[7]=(__bf16)a1.w;
        *(bf16x8*)&As[r][lane * 8] = t;
        const int ig = i0 + r;                            // diag column of this row
        if ((ig >> 3) == lane) {                          // this lane holds it
            const int c = ig & 7;
            float dv = (c==0)?a0.x:(c==1)?a0.y:(c==2)?a0.z:(c==3)?a0.w
                     :(c==4)?a1.x:(c==5)?a1.y:(c==6)?a1.z:a1.w;
            g_t[b * INn + ig] = dv;                       // fp32-exact diagonal
        }
    }
    __syncthreads();

    // ---- MFMA: As (A-operand, rows i) x Wbf (B-operand, rows p) ----
    const int p_base = wave * 48;
    f32x4 acc[4][3];
#pragma unroll
    for (int mi = 0; mi < 4; ++mi)
#pragma unroll
        for (int nf = 0; nf < 3; ++nf) acc[mi][nf] = (f32x4){0.f, 0.f, 0.f, 0.f};

    for (int kc = 0; kc < INn; kc += 32) {
        bf16x8 afr[4];
#pragma unroll
        for (int mi = 0; mi < 4; ++mi)
            afr[mi] = *(const bf16x8*)&As[mi * 16 + l15][kc + quad * 8];
#pragma unroll
        for (int nf = 0; nf < 3; ++nf) {
            const __bf16* bp = g_Wbf + (size_t)(p_base + nf * 16 + l15) * INn + kc + quad * 8;
            bf16x8 bfr = *(const bf16x8*)bp;
#pragma unroll
            for (int mi = 0; mi < 4; ++mi)
                acc[mi][nf] = __builtin_amdgcn_mfma_f32_16x16x32_bf16(afr[mi], bfr, acc[mi][nf], 0, 0, 0);
        }
    }

    // ---- store U[b][p][i] bf16 (4 consecutive i per lane -> 8B stores) ----
    __bf16* Ub = g_U + (size_t)b * (OUTn * INn);
#pragma unroll
    for (int mi = 0; mi < 4; ++mi) {
        const int ib = i0 + mi * 16 + quad * 4;
#pragma unroll
        for (int nf = 0; nf < 3; ++nf) {
            const int p = p_base + nf * 16 + l15;
            bf16x4 v;
            v[0] = (__bf16)acc[mi][nf][0];
            v[1] = (__bf16)acc[mi][nf][1];
            v[2] = (__bf16)acc[mi][nf][2];
            v[3] = (__bf16)acc[mi][nf][3];
            *(bf16x4*)(Ub + (size_t)p * INn + ib) = v;
        }
    }
}

// ---------------------------------------------------------------------------
// k2: mu_f[b,o] = mu[b,:]·W[o,:] + bias[o]
//     d[b,o]   = sum_i (diag_sigma[b,i] + mu[b,i]^2) * sp[o,i] + (o==b)*sbias[o]
// diag now comes from g_t (coalesced) instead of a 2052B-stride gather.
// ---------------------------------------------------------------------------
__global__ __launch_bounds__(256) void k2_kernel(const float* __restrict__ mu,
                                                 const float* __restrict__ W,
                                                 const float* __restrict__ bias,
                                                 const float* __restrict__ sbias,
                                                 float* __restrict__ out_muf) {
    const int b  = blockIdx.x;
    const int oq = blockIdx.y;   // 0..3
    __shared__ __align__(16) float muL[INn];
    __shared__ __align__(16) float tL[INn];
    const int tid = threadIdx.x;
    for (int i = tid; i < INn; i += 256) {
        float m = mu[b * INn + i];
        muL[i] = m;
        tL[i] = g_t[b * INn + i] + m * m;
    }
    __syncthreads();
    const int wave = tid >> 6, lane = tid & 63;
    const float4* Mr = (const float4*)muL;
    const float4* Tr = (const float4*)tL;
    float4 m0 = Mr[lane * 2], m1 = Mr[lane * 2 + 1];
    float4 t0 = Tr[lane * 2], t1 = Tr[lane * 2 + 1];
#pragma unroll 4
    for (int ow = 0; ow < 24; ++ow) {
        const int o = oq * 96 + wave * 24 + ow;
        const float4* Wr = (const float4*)(W + (size_t)o * INn);
        const float4* Sr = (const float4*)(g_sp + (size_t)o * INn);
        float4 w0 = Wr[lane * 2], w1 = Wr[lane * 2 + 1];
        float4 s0 = Sr[lane * 2], s1 = Sr[lane * 2 + 1];
        float mf = w0.x * m0.x + w0.y * m0.y + w0.z * m0.z + w0.w * m0.w
                 + w1.x * m1.x + w1.y * m1.y + w1.z * m1.z + w1.w * m1.w;
        float dd = s0.x * t0.x + s0.y * t0.y + s0.z * t0.z + s0.w * t0.w
                 + s1.x * t1.x + s1.y * t1.y + s1.z * t1.z + s1.w * t1.w;
#pragma unroll
        for (int off = 32; off; off >>= 1) {
            mf += __shfl_xor(mf, off, 64);
            dd += __shfl_xor(dd, off, 64);
        }
        if (lane == 0) {
            out_muf[b * OUTn + o] = mf + bias[o];
            g_d[b * OUTn + o] = dd + (o == b ? sbias[o] : 0.f);
        }
    }
}

// ---------------------------------------------------------------------------
// passB: out[b,o,p0+p] = sum_i Wbf[o,i] * U[b][p0+p][i]  (+ d[b,o] if o==p)
// grid (6 p-tiles, 384 b), 512 thr. U tile read exactly once (bf16, coalesced),
// staged to LDS; then the verified Stage-B MFMA + diag epilogue.
// ---------------------------------------------------------------------------
__global__ __launch_bounds__(512, 4) void passB_kernel(float* __restrict__ outS) {
    __shared__ __bf16 Ut[64][INn + 8];

    const int ptile = blockIdx.x;   // 0..5
    const int b     = blockIdx.y;   // 0..383
    const int tid   = threadIdx.x;
    const int wave  = tid >> 6, lane = tid & 63;
    const int quad  = lane >> 4, l15 = lane & 15;
    const int p0    = ptile * 64;

    // ---- stage U tile (64 p-rows x 512 i, bf16) ----
    const __bf16* Ub = g_U + ((size_t)b * OUTn + p0) * INn;
#pragma unroll
    for (int k = 0; k < 8; ++k) {
        const int r = k * 8 + wave;
        *(bf16x8*)&Ut[r][lane * 8] = *(const bf16x8*)(Ub + (size_t)r * INn + lane * 8);
    }
    __syncthreads();

    // ---- MFMA: Wbf rows (o) x Ut rows (p) ----
    const int o_base = wave * 48;
    f32x4 acc[3][4];
#pragma unroll
    for (int mi = 0; mi < 3; ++mi)
#pragma unroll
        for (int nf = 0; nf < 4; ++nf) acc[mi][nf] = (f32x4){0.f, 0.f, 0.f, 0.f};

    for (int kc = 0; kc < INn; kc += 32) {
        bf16x8 afr[3];
#pragma unroll
        for (int mi = 0; mi < 3; ++mi) {
            const __bf16* ap = g_Wbf + (size_t)(o_base + mi * 16 + l15) * INn + kc + quad * 8;
            afr[mi] = *(const bf16x8*)ap;
        }
#pragma unroll
        for (int nf = 0; nf < 4; ++nf) {
            bf16x8 bfr = *(const bf16x8*)&Ut[nf * 16 + l15][kc + quad * 8];
#pragma unroll
            for (int mi = 0; mi < 3; ++mi)
                acc[mi][nf] = __builtin_amdgcn_mfma_f32_16x16x32_bf16(afr[mi], bfr, acc[mi][nf], 0, 0, 0);
        }
    }

    // ---- epilogue: add diagonal, store fp32 ----
    float* outb = outS + (size_t)b * (OUTn * OUTn);
#pragma unroll
    for (int mi = 0; mi < 3; ++mi) {
        const int o_r = o_base + mi * 16 + quad * 4;
#pragma unroll
        for (int nf = 0; nf < 4; ++nf) {
            const int p = p0 + nf * 16 + l15;
#pragma unroll
            for (int r = 0; r < 4; ++r) {
                const int o = o_r + r;
                float v = acc[mi][nf][r];
                if (o == p) v += g_d[b * OUTn + o];
                outb[(size_t)o * OUTn + p] = v;
            }
        }
    }
}

// ---------------------------------------------------------------------------
extern "C" void kernel_launch(void* const* d_in, const int* in_sizes, int n_in,
                              void* d_out, int out_size, void* d_ws, size_t ws_size,
                              hipStream_t stream) {
    const float* mu    = (const float*)d_in[0];
    const float* sigma = (const float*)d_in[1];
    const float* W     = (const float*)d_in[2];
    const float* bias  = (const float*)d_in[3];
    const float* sw    = (const float*)d_in[4];
    const float* sbias = (const float*)d_in[5];

    float* out     = (float*)d_out;
    float* out_muf = out;                  // [384, 384]
    float* out_sig = out + Bn * OUTn;      // [384, 384, 384]

    prep_kernel<<<(OUTn * INn + 255) / 256, 256, 0, stream>>>(W, sw);
    passA_kernel<<<dim3(8, Bn), 512, 0, stream>>>(sigma);           // writes g_U, g_t
    k2_kernel<<<dim3(Bn, 4), 256, 0, stream>>>(mu, W, bias, sbias, out_muf); // writes g_d
    passB_kernel<<<dim3(6, Bn), 512, 0, stream>>>(out_sig);
}